// Round 1
// baseline (989.445 us; speedup 1.0000x reference)
//
#include <hip/hip_runtime.h>

#define N_NODES 50000
#define E_EDGES 800000
#define IN_DIM 256
#define H_HEADS 4
#define F_OUT 64
#define EF_DIM 64
#define NT_TYPES 8
#define SLOPE 0.2f
#define HF 256  /* H*F */

// workspace layout (in float elements)
#define FEAT_OFF 0            /* N*H*F = 12,800,000 */
#define EL_OFF   12800000     /* N*H = 200,000 */
#define ER_OFF   13000000
#define SSUM_OFF 13200000
#define SMAX_OFF 13400000     /* uint-encoded */
#define EE_OFF   13600000     /* NT*H = 32 */

// ---------------- GEMM: feat = nfeat @ fc_w, fused el/er ----------------
// block = 256 threads, tile = 16 rows x 256 cols, K-chunks of 32.
__global__ __launch_bounds__(256) void gemm_feat_kernel(
    const float* __restrict__ nfeat, const float* __restrict__ fc_w,
    const float* __restrict__ attn_l, const float* __restrict__ attn_r,
    float* __restrict__ feat, float* __restrict__ el, float* __restrict__ er)
{
    __shared__ __align__(16) float As[32 * 16];    // [k][r] transposed
    __shared__ __align__(16) float Bs[32 * 256];   // [k][c]
    const int t  = threadIdx.x;
    const int cx = t & 63;      // lane id within wave; owns cols cx*4..cx*4+3
    const int ry = t >> 6;      // wave id; owns rows ry*4..ry*4+3
    const int row0 = blockIdx.x * 16;

    float acc[4][4] = {};

    for (int kb = 0; kb < IN_DIM; kb += 32) {
        __syncthreads();
        // stage A tile: 16 rows x 32 k, transposed into As[k][r]
        if (t < 128) {
            const int r = t >> 3, k4 = t & 7;
            const float4 v = *(const float4*)(nfeat + (size_t)(row0 + r) * IN_DIM + kb + k4 * 4);
            As[(k4 * 4 + 0) * 16 + r] = v.x;
            As[(k4 * 4 + 1) * 16 + r] = v.y;
            As[(k4 * 4 + 2) * 16 + r] = v.z;
            As[(k4 * 4 + 3) * 16 + r] = v.w;
        }
        // stage B tile: 32 k x 256 c  (8 float4 per thread)
        #pragma unroll
        for (int i = 0; i < 8; i++) {
            const int f4 = i * 256 + t;      // float4 index = k*64 + c4
            const int k = f4 >> 6, c4 = f4 & 63;
            *(float4*)(Bs + k * 256 + c4 * 4) =
                *(const float4*)(fc_w + (size_t)(kb + k) * HF + c4 * 4);
        }
        __syncthreads();
        #pragma unroll
        for (int k = 0; k < 32; k++) {
            const float4 a4 = *(const float4*)(&As[k * 16 + ry * 4]);
            const float4 b4 = *(const float4*)(&Bs[k * 256 + cx * 4]);
            const float ar_[4] = {a4.x, a4.y, a4.z, a4.w};
            const float bc_[4] = {b4.x, b4.y, b4.z, b4.w};
            #pragma unroll
            for (int rr = 0; rr < 4; rr++)
                #pragma unroll
                for (int cc = 0; cc < 4; cc++)
                    acc[rr][cc] = fmaf(ar_[rr], bc_[cc], acc[rr][cc]);
        }
    }

    // epilogue: write feat, fused el/er partial dots + 16-lane reduction
    const float4 al = *(const float4*)(attn_l + cx * 4);  // attn_l flat [H*F]=[256]
    const float4 ar4 = *(const float4*)(attn_r + cx * 4);
    const int h = cx >> 4;  // head of this lane's column group
    #pragma unroll
    for (int rr = 0; rr < 4; rr++) {
        const int row = row0 + ry * 4 + rr;
        float4 o;
        o.x = acc[rr][0]; o.y = acc[rr][1]; o.z = acc[rr][2]; o.w = acc[rr][3];
        *(float4*)(feat + (size_t)row * HF + cx * 4) = o;
        float pl = o.x * al.x + o.y * al.y + o.z * al.z + o.w * al.w;
        float pr = o.x * ar4.x + o.y * ar4.y + o.z * ar4.z + o.w * ar4.w;
        #pragma unroll
        for (int m = 8; m >= 1; m >>= 1) {
            pl += __shfl_xor(pl, m);
            pr += __shfl_xor(pr, m);
        }
        if ((cx & 15) == 0) {
            el[row * H_HEADS + h] = pl;
            er[row * H_HEADS + h] = pr;
        }
    }
}

// ---------------- ee[NT,H] = einsum over fc_e(edge_emb) ----------------
__global__ __launch_bounds__(256) void ee_kernel(
    const float* __restrict__ edge_emb, const float* __restrict__ fc_e_w,
    const float* __restrict__ attn_e, float* __restrict__ ee)
{
    const int c = threadIdx.x;          // 0..255 = h*64 + e
    const float ae = attn_e[c];
    const int lane = c & 63, h = c >> 6;
    for (int ty = 0; ty < NT_TYPES; ty++) {
        float v = 0.f;
        #pragma unroll 8
        for (int k = 0; k < EF_DIM; k++)
            v = fmaf(edge_emb[ty * EF_DIM + k], fc_e_w[k * (H_HEADS * EF_DIM) + c], v);
        float contrib = v * ae;
        #pragma unroll
        for (int m = 32; m >= 1; m >>= 1) contrib += __shfl_xor(contrib, m);
        if (lane == 0) ee[ty * H_HEADS + h] = contrib;
    }
}

// ---------------- edge pass 1: raw scores + segment max ----------------
__global__ __launch_bounds__(256) void pass1_kernel(
    const int* __restrict__ src, const int* __restrict__ dst, const int* __restrict__ etype,
    const float* __restrict__ el, const float* __restrict__ er, const float* __restrict__ ee,
    float* __restrict__ a_out, unsigned* __restrict__ smax)
{
    const int t = blockIdx.x * 256 + threadIdx.x;
    if (t >= E_EDGES * H_HEADS) return;
    const int e = t >> 2, h = t & 3;
    const int s = src[e], d = dst[e], ty = etype[e];
    const float v = el[s * 4 + h] + er[d * 4 + h] + ee[ty * 4 + h];
    const float araw = v > 0.f ? v : SLOPE * v;
    a_out[t] = araw;
    unsigned u = __float_as_uint(araw);
    u = (u & 0x80000000u) ? ~u : (u | 0x80000000u);  // order-preserving encode
    atomicMax(smax + d * 4 + h, u);
}

// ---------------- edge pass 2: exp + segment sum ----------------
__global__ __launch_bounds__(256) void pass2_kernel(
    const int* __restrict__ dst, const unsigned* __restrict__ smax,
    float* __restrict__ a_out, float* __restrict__ ssum)
{
    const int t = blockIdx.x * 256 + threadIdx.x;
    if (t >= E_EDGES * H_HEADS) return;
    const int e = t >> 2, h = t & 3;
    const int d = dst[e];
    const unsigned u = smax[d * 4 + h];
    const float m = (u & 0x80000000u) ? __uint_as_float(u ^ 0x80000000u)
                                      : __uint_as_float(~u);
    const float ex = __expf(a_out[t] - m);
    a_out[t] = ex;
    atomicAdd(ssum + d * 4 + h, ex);
}

// ---------------- edge pass 3: normalize + weighted aggregation ----------------
__global__ __launch_bounds__(256) void pass3_kernel(
    const int* __restrict__ src, const int* __restrict__ dst,
    const float* __restrict__ feat, const float* __restrict__ ssum,
    float* __restrict__ a_out, float* __restrict__ rst)
{
    const int h = threadIdx.x >> 6, f = threadIdx.x & 63;
    for (int e = blockIdx.x; e < E_EDGES; e += gridDim.x) {
        const int s = src[e], d = dst[e];
        const float aexp = a_out[e * 4 + h];
        const float a = aexp / ssum[d * 4 + h];
        if (f == 0) a_out[e * 4 + h] = a;  // final attention output
        const float v = feat[(size_t)s * HF + h * F_OUT + f];
        atomicAdd(rst + (size_t)d * HF + h * F_OUT + f, a * v);
    }
}

extern "C" void kernel_launch(void* const* d_in, const int* in_sizes, int n_in,
                              void* d_out, int out_size, void* d_ws, size_t ws_size,
                              hipStream_t stream) {
    const float* nfeat    = (const float*)d_in[0];
    const float* fc_w     = (const float*)d_in[1];
    const float* fc_e_w   = (const float*)d_in[2];
    const float* attn_l   = (const float*)d_in[3];
    const float* attn_r   = (const float*)d_in[4];
    const float* attn_e   = (const float*)d_in[5];
    const float* edge_emb = (const float*)d_in[6];
    const int*   src      = (const int*)d_in[7];
    const int*   dst      = (const int*)d_in[8];
    const int*   etype    = (const int*)d_in[9];

    float* ws   = (float*)d_ws;
    float* feat = ws + FEAT_OFF;
    float* el   = ws + EL_OFF;
    float* er   = ws + ER_OFF;
    float* ssum = ws + SSUM_OFF;
    unsigned* smax = (unsigned*)(ws + SMAX_OFF);
    float* ee   = ws + EE_OFF;

    float* rst   = (float*)d_out;                              // [N,H,F]
    float* a_out = (float*)d_out + (size_t)N_NODES * HF;       // [E,H]

    // zero-init accumulators (0x00 == -inf in the ordered-uint max encoding)
    hipMemsetAsync(rst, 0, (size_t)N_NODES * HF * sizeof(float), stream);
    hipMemsetAsync(ssum, 0, (size_t)N_NODES * H_HEADS * sizeof(float), stream);
    hipMemsetAsync(smax, 0, (size_t)N_NODES * H_HEADS * sizeof(unsigned), stream);

    gemm_feat_kernel<<<N_NODES / 16, 256, 0, stream>>>(nfeat, fc_w, attn_l, attn_r, feat, el, er);
    ee_kernel<<<1, 256, 0, stream>>>(edge_emb, fc_e_w, attn_e, ee);

    const int EH = E_EDGES * H_HEADS;
    pass1_kernel<<<(EH + 255) / 256, 256, 0, stream>>>(src, dst, etype, el, er, ee, a_out, smax);
    pass2_kernel<<<(EH + 255) / 256, 256, 0, stream>>>(dst, smax, a_out, ssum);
    pass3_kernel<<<16384, 256, 0, stream>>>(src, dst, feat, ssum, a_out, rst);
}

// Round 2
// 612.450 us; speedup vs baseline: 1.6156x; 1.6156x over previous
//
#include <hip/hip_runtime.h>

#define N_NODES 50000
#define E_EDGES 800000
#define IN_DIM 256
#define H_HEADS 4
#define F_OUT 64
#define EF_DIM 64
#define NT_TYPES 8
#define SLOPE 0.2f
#define HF 256  /* H*F */

// workspace layout (float element offsets)
#define FEAT_OFF 0            /* N*H*F = 12,800,000 */
#define EL_OFF   12800000     /* N*H = 200,000 */
#define ER_OFF   13000000
#define EE_OFF   13200000     /* 32, padded */
#define INT_OFF  13200064     /* int region starts here */
// int offsets within int region
#define DEG_IOFF     0        /* 50,000 */
#define ROWOFF_IOFF  50000    /* 50,001 */
#define CURSOR_IOFF  100008
#define PERM_IOFF    150008   /* 800,000 */

// ---------------- GEMM: feat = nfeat @ fc_w, fused el/er ----------------
__global__ __launch_bounds__(256) void gemm_feat_kernel(
    const float* __restrict__ nfeat, const float* __restrict__ fc_w,
    const float* __restrict__ attn_l, const float* __restrict__ attn_r,
    float* __restrict__ feat, float* __restrict__ el, float* __restrict__ er)
{
    __shared__ __align__(16) float As[32 * 16];    // [k][r] transposed
    __shared__ __align__(16) float Bs[32 * 256];   // [k][c]
    const int t  = threadIdx.x;
    const int cx = t & 63;
    const int ry = t >> 6;
    const int row0 = blockIdx.x * 16;

    float acc[4][4] = {};

    for (int kb = 0; kb < IN_DIM; kb += 32) {
        __syncthreads();
        if (t < 128) {
            const int r = t >> 3, k4 = t & 7;
            const float4 v = *(const float4*)(nfeat + (size_t)(row0 + r) * IN_DIM + kb + k4 * 4);
            As[(k4 * 4 + 0) * 16 + r] = v.x;
            As[(k4 * 4 + 1) * 16 + r] = v.y;
            As[(k4 * 4 + 2) * 16 + r] = v.z;
            As[(k4 * 4 + 3) * 16 + r] = v.w;
        }
        #pragma unroll
        for (int i = 0; i < 8; i++) {
            const int f4 = i * 256 + t;
            const int k = f4 >> 6, c4 = f4 & 63;
            *(float4*)(Bs + k * 256 + c4 * 4) =
                *(const float4*)(fc_w + (size_t)(kb + k) * HF + c4 * 4);
        }
        __syncthreads();
        #pragma unroll
        for (int k = 0; k < 32; k++) {
            const float4 a4 = *(const float4*)(&As[k * 16 + ry * 4]);
            const float4 b4 = *(const float4*)(&Bs[k * 256 + cx * 4]);
            const float ar_[4] = {a4.x, a4.y, a4.z, a4.w};
            const float bc_[4] = {b4.x, b4.y, b4.z, b4.w};
            #pragma unroll
            for (int rr = 0; rr < 4; rr++)
                #pragma unroll
                for (int cc = 0; cc < 4; cc++)
                    acc[rr][cc] = fmaf(ar_[rr], bc_[cc], acc[rr][cc]);
        }
    }

    const float4 al = *(const float4*)(attn_l + cx * 4);
    const float4 ar4 = *(const float4*)(attn_r + cx * 4);
    const int h = cx >> 4;
    #pragma unroll
    for (int rr = 0; rr < 4; rr++) {
        const int row = row0 + ry * 4 + rr;
        float4 o;
        o.x = acc[rr][0]; o.y = acc[rr][1]; o.z = acc[rr][2]; o.w = acc[rr][3];
        *(float4*)(feat + (size_t)row * HF + cx * 4) = o;
        float pl = o.x * al.x + o.y * al.y + o.z * al.z + o.w * al.w;
        float pr = o.x * ar4.x + o.y * ar4.y + o.z * ar4.z + o.w * ar4.w;
        #pragma unroll
        for (int m = 8; m >= 1; m >>= 1) {
            pl += __shfl_xor(pl, m);
            pr += __shfl_xor(pr, m);
        }
        if ((cx & 15) == 0) {
            el[row * H_HEADS + h] = pl;
            er[row * H_HEADS + h] = pr;
        }
    }
}

// ---------------- ee[NT,H] ----------------
__global__ __launch_bounds__(256) void ee_kernel(
    const float* __restrict__ edge_emb, const float* __restrict__ fc_e_w,
    const float* __restrict__ attn_e, float* __restrict__ ee)
{
    const int c = threadIdx.x;
    const float ae = attn_e[c];
    const int lane = c & 63, h = c >> 6;
    for (int ty = 0; ty < NT_TYPES; ty++) {
        float v = 0.f;
        #pragma unroll 8
        for (int k = 0; k < EF_DIM; k++)
            v = fmaf(edge_emb[ty * EF_DIM + k], fc_e_w[k * (H_HEADS * EF_DIM) + c], v);
        float contrib = v * ae;
        #pragma unroll
        for (int m = 32; m >= 1; m >>= 1) contrib += __shfl_xor(contrib, m);
        if (lane == 0) ee[ty * H_HEADS + h] = contrib;
    }
}

// ---------------- CSR build ----------------
__global__ __launch_bounds__(256) void hist_kernel(
    const int* __restrict__ dst, int* __restrict__ deg)
{
    const int t = blockIdx.x * 256 + threadIdx.x;
    if (t < E_EDGES) atomicAdd(deg + dst[t], 1);
}

#define SCAN_CHUNK 196  /* 256*196 >= 50000 */
__global__ __launch_bounds__(256) void scan_kernel(
    const int* __restrict__ deg, int* __restrict__ row_off)
{
    __shared__ int part[256];
    const int t = threadIdx.x;
    const int start = t * SCAN_CHUNK;
    int s = 0;
    for (int j = 0; j < SCAN_CHUNK; j++) {
        const int g = start + j;
        if (g < N_NODES) s += deg[g];
    }
    part[t] = s;
    __syncthreads();
    if (t == 0) {
        int acc = 0;
        for (int i = 0; i < 256; i++) { const int v = part[i]; part[i] = acc; acc += v; }
    }
    __syncthreads();
    int running = part[t];
    for (int j = 0; j < SCAN_CHUNK; j++) {
        const int g = start + j;
        if (g >= N_NODES) break;
        row_off[g] = running;
        running += deg[g];
    }
    if (start <= N_NODES && N_NODES < start + SCAN_CHUNK) row_off[N_NODES] = running;
}

__global__ __launch_bounds__(256) void scatter_kernel(
    const int* __restrict__ dst, const int* __restrict__ row_off,
    int* __restrict__ cursor, int* __restrict__ perm)
{
    const int t = blockIdx.x * 256 + threadIdx.x;
    if (t >= E_EDGES) return;
    const int d = dst[t];
    const int pos = row_off[d] + atomicAdd(cursor + d, 1);
    perm[pos] = t;
}

// ---------------- fused softmax + aggregation, one block per dst node ----------------
__global__ __launch_bounds__(256) void agg_kernel(
    const int* __restrict__ src, const int* __restrict__ etype,
    const int* __restrict__ perm, const int* __restrict__ row_off,
    const float* __restrict__ el, const float* __restrict__ er,
    const float* __restrict__ ee, const float* __restrict__ feat,
    float* __restrict__ a_out, float* __restrict__ rst)
{
    const int d = blockIdx.x;
    const int h = threadIdx.x >> 6, lane = threadIdx.x & 63;
    const int off = row_off[d];
    const int deg = row_off[d + 1] - off;
    __shared__ float p[4][128];

    const float erh = er[d * 4 + h];

    float m = -INFINITY;
    for (int i = lane; i < deg; i += 64) {
        const int e = perm[off + i];
        float sc = el[src[e] * 4 + h] + erh + ee[etype[e] * 4 + h];
        sc = sc > 0.f ? sc : SLOPE * sc;
        m = fmaxf(m, sc);
    }
    #pragma unroll
    for (int w = 32; w >= 1; w >>= 1) m = fmaxf(m, __shfl_xor(m, w));

    float acc = 0.f;
    if (deg <= 128) {
        float s = 0.f;
        for (int i = lane; i < deg; i += 64) {
            const int e = perm[off + i];
            float sc = el[src[e] * 4 + h] + erh + ee[etype[e] * 4 + h];
            sc = sc > 0.f ? sc : SLOPE * sc;
            const float pe = __expf(sc - m);
            p[h][i] = pe;
            s += pe;
        }
        #pragma unroll
        for (int w = 32; w >= 1; w >>= 1) s += __shfl_xor(s, w);
        const float inv = 1.f / s;
        for (int i = lane; i < deg; i += 64)
            a_out[perm[off + i] * 4 + h] = p[h][i] * inv;
        for (int i = 0; i < deg; i++) {
            const int e = perm[off + i];
            acc = fmaf(p[h][i] * inv, feat[(size_t)src[e] * HF + h * 64 + lane], acc);
        }
    } else {
        float s = 0.f;
        for (int i = lane; i < deg; i += 64) {
            const int e = perm[off + i];
            float sc = el[src[e] * 4 + h] + erh + ee[etype[e] * 4 + h];
            sc = sc > 0.f ? sc : SLOPE * sc;
            s += __expf(sc - m);
        }
        #pragma unroll
        for (int w = 32; w >= 1; w >>= 1) s += __shfl_xor(s, w);
        const float inv = 1.f / s;
        for (int i = 0; i < deg; i++) {
            const int e = perm[off + i];
            const int sn = src[e];
            float sc = el[sn * 4 + h] + erh + ee[etype[e] * 4 + h];
            sc = sc > 0.f ? sc : SLOPE * sc;
            const float a = __expf(sc - m) * inv;
            if (lane == 0) a_out[e * 4 + h] = a;
            acc = fmaf(a, feat[(size_t)sn * HF + h * 64 + lane], acc);
        }
    }
    rst[(size_t)d * HF + h * 64 + lane] = acc;
}

extern "C" void kernel_launch(void* const* d_in, const int* in_sizes, int n_in,
                              void* d_out, int out_size, void* d_ws, size_t ws_size,
                              hipStream_t stream) {
    const float* nfeat    = (const float*)d_in[0];
    const float* fc_w     = (const float*)d_in[1];
    const float* fc_e_w   = (const float*)d_in[2];
    const float* attn_l   = (const float*)d_in[3];
    const float* attn_r   = (const float*)d_in[4];
    const float* attn_e   = (const float*)d_in[5];
    const float* edge_emb = (const float*)d_in[6];
    const int*   src      = (const int*)d_in[7];
    const int*   dst      = (const int*)d_in[8];
    const int*   etype    = (const int*)d_in[9];

    float* ws   = (float*)d_ws;
    float* feat = ws + FEAT_OFF;
    float* el   = ws + EL_OFF;
    float* er   = ws + ER_OFF;
    float* ee   = ws + EE_OFF;
    int*   ip      = (int*)(ws + INT_OFF);
    int*   deg     = ip + DEG_IOFF;
    int*   row_off = ip + ROWOFF_IOFF;
    int*   cursor  = ip + CURSOR_IOFF;
    int*   perm    = ip + PERM_IOFF;

    float* rst   = (float*)d_out;                              // [N,H,F]
    float* a_out = (float*)d_out + (size_t)N_NODES * HF;       // [E,H]

    hipMemsetAsync(deg, 0, N_NODES * sizeof(int), stream);
    hipMemsetAsync(cursor, 0, N_NODES * sizeof(int), stream);

    gemm_feat_kernel<<<N_NODES / 16, 256, 0, stream>>>(nfeat, fc_w, attn_l, attn_r, feat, el, er);
    ee_kernel<<<1, 256, 0, stream>>>(edge_emb, fc_e_w, attn_e, ee);

    const int EB = (E_EDGES + 255) / 256;
    hist_kernel<<<EB, 256, 0, stream>>>(dst, deg);
    scan_kernel<<<1, 256, 0, stream>>>(deg, row_off);
    scatter_kernel<<<EB, 256, 0, stream>>>(dst, row_off, cursor, perm);

    agg_kernel<<<N_NODES, 256, 0, stream>>>(src, etype, perm, row_off,
                                            el, er, ee, feat, a_out, rst);
}

// Round 3
// 544.840 us; speedup vs baseline: 1.8160x; 1.1241x over previous
//
#include <hip/hip_runtime.h>

#define N_NODES 50000
#define E_EDGES 800000
#define IN_DIM 256
#define H_HEADS 4
#define F_OUT 64
#define EF_DIM 64
#define NT_TYPES 8
#define SLOPE 0.2f
#define HF 256  /* H*F */

typedef __attribute__((ext_vector_type(8))) short short8;
typedef __attribute__((ext_vector_type(4))) float f32x4;
typedef unsigned short ushort_t;

// workspace layout (float element offsets)
#define FEATBF_OFF 0          /* N*HF bf16 = 12.8M ushorts = 6.4M floats */
#define EL_OFF   6400000      /* N*H = 200,000 */
#define ER_OFF   6600000
#define EE_OFF   6800000      /* 32, padded to 64 */
#define BT_OFF   6800064      /* 256x256 bf16 = 65536 ushorts = 32768 floats */
#define INT_OFF  6832832
// int offsets within int region
#define DEG_IOFF     0        /* 50,000 */
#define CURSOR_IOFF  50000    /* 50,000 (adjacent to deg for single memset) */
#define ROWOFF_IOFF  100000   /* 50,001 */
#define PERM_IOFF    150008   /* 800,000 */

__device__ __forceinline__ ushort_t f2bf(float f) {
    unsigned u = __float_as_uint(f);
    u += 0x7fffu + ((u >> 16) & 1u);   // round-nearest-even
    return (ushort_t)(u >> 16);
}
__device__ __forceinline__ float bf2f(ushort_t b) {
    return __uint_as_float(((unsigned)b) << 16);
}

// ---------------- cast + transpose fc_w -> Bt[c][k] bf16 ----------------
__global__ __launch_bounds__(256) void cast_w_kernel(
    const float* __restrict__ fc_w, ushort_t* __restrict__ Bt)
{
    const int k = blockIdx.x, c = threadIdx.x;
    Bt[(size_t)c * 256 + k] = f2bf(fc_w[(size_t)k * 256 + c]);
}

// ---------------- MFMA GEMM: feat_bf16 = bf16(nfeat) @ bf16(fc_w), fused el/er ----------------
// block = 256 = 4 waves; wave w owns head w (cols w*64..w*64+64); 64 rows per block.
__global__ __launch_bounds__(256) void gemm_feat_mfma(
    const float* __restrict__ nfeat, const ushort_t* __restrict__ Bt,
    const float* __restrict__ attn_l, const float* __restrict__ attn_r,
    ushort_t* __restrict__ feat, float* __restrict__ el, float* __restrict__ er)
{
    const int w    = threadIdx.x >> 6;   // wave id == head
    const int lane = threadIdx.x & 63;
    const int n16  = lane & 15;
    const int quad = lane >> 4;
    const int row0 = blockIdx.x * 64;

    f32x4 acc[4][4];
    #pragma unroll
    for (int rt = 0; rt < 4; rt++)
        #pragma unroll
        for (int ct = 0; ct < 4; ct++)
            acc[rt][ct] = (f32x4){0.f, 0.f, 0.f, 0.f};

    for (int kb = 0; kb < IN_DIM; kb += 32) {
        short8 a[4], b[4];
        #pragma unroll
        for (int rt = 0; rt < 4; rt++) {
            int r = row0 + rt * 16 + n16;
            r = r < N_NODES ? r : N_NODES - 1;          // clamp (tail block)
            const float* p = nfeat + (size_t)r * IN_DIM + kb + quad * 8;
            const float4 v0 = *(const float4*)p;
            const float4 v1 = *(const float4*)(p + 4);
            short8 t;
            t[0] = (short)f2bf(v0.x); t[1] = (short)f2bf(v0.y);
            t[2] = (short)f2bf(v0.z); t[3] = (short)f2bf(v0.w);
            t[4] = (short)f2bf(v1.x); t[5] = (short)f2bf(v1.y);
            t[6] = (short)f2bf(v1.z); t[7] = (short)f2bf(v1.w);
            a[rt] = t;
        }
        #pragma unroll
        for (int ct = 0; ct < 4; ct++) {
            const int c = w * 64 + ct * 16 + n16;
            b[ct] = *(const short8*)(Bt + (size_t)c * 256 + kb + quad * 8);
        }
        #pragma unroll
        for (int rt = 0; rt < 4; rt++)
            #pragma unroll
            for (int ct = 0; ct < 4; ct++)
                acc[rt][ct] = __builtin_amdgcn_mfma_f32_16x16x32_bf16(a[rt], b[ct], acc[rt][ct], 0, 0, 0);
    }

    // epilogue: feat store (bf16) + fused el/er
    float alv[4], arv[4];
    #pragma unroll
    for (int ct = 0; ct < 4; ct++) {
        alv[ct] = attn_l[w * 64 + ct * 16 + n16];
        arv[ct] = attn_r[w * 64 + ct * 16 + n16];
    }
    #pragma unroll
    for (int rt = 0; rt < 4; rt++) {
        #pragma unroll
        for (int reg = 0; reg < 4; reg++) {
            const int row = row0 + rt * 16 + quad * 4 + reg;
            const bool ok = row < N_NODES;
            float pl = 0.f, pr = 0.f;
            #pragma unroll
            for (int ct = 0; ct < 4; ct++) {
                const float v = acc[rt][ct][reg];
                if (ok) feat[(size_t)row * HF + w * 64 + ct * 16 + n16] = f2bf(v);
                pl = fmaf(v, alv[ct], pl);
                pr = fmaf(v, arv[ct], pr);
            }
            #pragma unroll
            for (int m = 8; m >= 1; m >>= 1) {
                pl += __shfl_xor(pl, m);
                pr += __shfl_xor(pr, m);
            }
            if (n16 == 0 && ok) {
                el[row * H_HEADS + w] = pl;
                er[row * H_HEADS + w] = pr;
            }
        }
    }
}

// ---------------- ee[NT,H] ----------------
__global__ __launch_bounds__(256) void ee_kernel(
    const float* __restrict__ edge_emb, const float* __restrict__ fc_e_w,
    const float* __restrict__ attn_e, float* __restrict__ ee)
{
    const int c = threadIdx.x;
    const float ae = attn_e[c];
    const int lane = c & 63, h = c >> 6;
    for (int ty = 0; ty < NT_TYPES; ty++) {
        float v = 0.f;
        #pragma unroll 8
        for (int k = 0; k < EF_DIM; k++)
            v = fmaf(edge_emb[ty * EF_DIM + k], fc_e_w[k * (H_HEADS * EF_DIM) + c], v);
        float contrib = v * ae;
        #pragma unroll
        for (int m = 32; m >= 1; m >>= 1) contrib += __shfl_xor(contrib, m);
        if (lane == 0) ee[ty * H_HEADS + h] = contrib;
    }
}

// ---------------- CSR build ----------------
__global__ __launch_bounds__(256) void hist_kernel(
    const int* __restrict__ dst, int* __restrict__ deg)
{
    const int t = blockIdx.x * 256 + threadIdx.x;
    if (t < E_EDGES) atomicAdd(deg + dst[t], 1);
}

#define SCAN_CHUNK 196  /* 256*196 >= 50000 */
__global__ __launch_bounds__(256) void scan_kernel(
    const int* __restrict__ deg, int* __restrict__ row_off)
{
    __shared__ int part[256];
    const int t = threadIdx.x;
    const int start = t * SCAN_CHUNK;
    int s = 0;
    for (int j = 0; j < SCAN_CHUNK; j++) {
        const int g = start + j;
        if (g < N_NODES) s += deg[g];
    }
    part[t] = s;
    __syncthreads();
    if (t == 0) {
        int acc = 0;
        for (int i = 0; i < 256; i++) { const int v = part[i]; part[i] = acc; acc += v; }
    }
    __syncthreads();
    int running = part[t];
    for (int j = 0; j < SCAN_CHUNK; j++) {
        const int g = start + j;
        if (g >= N_NODES) break;
        row_off[g] = running;
        running += deg[g];
    }
    if (start <= N_NODES && N_NODES < start + SCAN_CHUNK) row_off[N_NODES] = running;
}

__global__ __launch_bounds__(256) void scatter_kernel(
    const int* __restrict__ dst, const int* __restrict__ row_off,
    int* __restrict__ cursor, int* __restrict__ perm)
{
    const int t = blockIdx.x * 256 + threadIdx.x;
    if (t >= E_EDGES) return;
    const int d = dst[t];
    const int pos = row_off[d] + atomicAdd(cursor + d, 1);
    perm[pos] = t;
}

// ---------------- fused softmax + aggregation, one block per dst node ----------------
__global__ __launch_bounds__(256) void agg_kernel(
    const int* __restrict__ src, const int* __restrict__ etype,
    const int* __restrict__ perm, const int* __restrict__ row_off,
    const float* __restrict__ el, const float* __restrict__ er,
    const float* __restrict__ ee, const ushort_t* __restrict__ feat,
    float* __restrict__ a_out, float* __restrict__ rst)
{
    const int d = blockIdx.x;
    const int h = threadIdx.x >> 6, lane = threadIdx.x & 63;
    const int off = row_off[d];
    const int deg = row_off[d + 1] - off;
    __shared__ float p[4][128];

    const float erh = er[d * 4 + h];

    float m = -INFINITY;
    for (int i = lane; i < deg; i += 64) {
        const int e = perm[off + i];
        float sc = el[src[e] * 4 + h] + erh + ee[etype[e] * 4 + h];
        sc = sc > 0.f ? sc : SLOPE * sc;
        m = fmaxf(m, sc);
    }
    #pragma unroll
    for (int w = 32; w >= 1; w >>= 1) m = fmaxf(m, __shfl_xor(m, w));

    float acc = 0.f;
    if (deg <= 128) {
        float s = 0.f;
        for (int i = lane; i < deg; i += 64) {
            const int e = perm[off + i];
            float sc = el[src[e] * 4 + h] + erh + ee[etype[e] * 4 + h];
            sc = sc > 0.f ? sc : SLOPE * sc;
            const float pe = __expf(sc - m);
            p[h][i] = pe;
            s += pe;
        }
        #pragma unroll
        for (int w = 32; w >= 1; w >>= 1) s += __shfl_xor(s, w);
        const float inv = 1.f / s;
        for (int i = lane; i < deg; i += 64)
            a_out[perm[off + i] * 4 + h] = p[h][i] * inv;
        for (int i = 0; i < deg; i++) {
            const int e = perm[off + i];
            const float v = bf2f(feat[(size_t)src[e] * HF + h * 64 + lane]);
            acc = fmaf(p[h][i] * inv, v, acc);
        }
    } else {
        float s = 0.f;
        for (int i = lane; i < deg; i += 64) {
            const int e = perm[off + i];
            float sc = el[src[e] * 4 + h] + erh + ee[etype[e] * 4 + h];
            sc = sc > 0.f ? sc : SLOPE * sc;
            s += __expf(sc - m);
        }
        #pragma unroll
        for (int w = 32; w >= 1; w >>= 1) s += __shfl_xor(s, w);
        const float inv = 1.f / s;
        for (int i = 0; i < deg; i++) {
            const int e = perm[off + i];
            const int sn = src[e];
            float sc = el[sn * 4 + h] + erh + ee[etype[e] * 4 + h];
            sc = sc > 0.f ? sc : SLOPE * sc;
            const float a = __expf(sc - m) * inv;
            if (lane == 0) a_out[e * 4 + h] = a;
            const float v = bf2f(feat[(size_t)sn * HF + h * 64 + lane]);
            acc = fmaf(a, v, acc);
        }
    }
    rst[(size_t)d * HF + h * 64 + lane] = acc;
}

extern "C" void kernel_launch(void* const* d_in, const int* in_sizes, int n_in,
                              void* d_out, int out_size, void* d_ws, size_t ws_size,
                              hipStream_t stream) {
    const float* nfeat    = (const float*)d_in[0];
    const float* fc_w     = (const float*)d_in[1];
    const float* fc_e_w   = (const float*)d_in[2];
    const float* attn_l   = (const float*)d_in[3];
    const float* attn_r   = (const float*)d_in[4];
    const float* attn_e   = (const float*)d_in[5];
    const float* edge_emb = (const float*)d_in[6];
    const int*   src      = (const int*)d_in[7];
    const int*   dst      = (const int*)d_in[8];
    const int*   etype    = (const int*)d_in[9];

    float* ws = (float*)d_ws;
    ushort_t* feat = (ushort_t*)(ws + FEATBF_OFF);
    float* el   = ws + EL_OFF;
    float* er   = ws + ER_OFF;
    float* ee   = ws + EE_OFF;
    ushort_t* Bt = (ushort_t*)(ws + BT_OFF);
    int*   ip      = (int*)(ws + INT_OFF);
    int*   deg     = ip + DEG_IOFF;
    int*   cursor  = ip + CURSOR_IOFF;
    int*   row_off = ip + ROWOFF_IOFF;
    int*   perm    = ip + PERM_IOFF;

    float* rst   = (float*)d_out;                              // [N,H,F]
    float* a_out = (float*)d_out + (size_t)N_NODES * HF;       // [E,H]

    // deg + cursor are adjacent: single memset
    hipMemsetAsync(deg, 0, 2 * N_NODES * sizeof(int), stream);

    cast_w_kernel<<<256, 256, 0, stream>>>(fc_w, Bt);
    gemm_feat_mfma<<<(N_NODES + 63) / 64, 256, 0, stream>>>(nfeat, Bt, attn_l, attn_r, feat, el, er);
    ee_kernel<<<1, 256, 0, stream>>>(edge_emb, fc_e_w, attn_e, ee);

    const int EB = (E_EDGES + 255) / 256;
    hist_kernel<<<EB, 256, 0, stream>>>(dst, deg);
    scan_kernel<<<1, 256, 0, stream>>>(deg, row_off);
    scatter_kernel<<<EB, 256, 0, stream>>>(dst, row_off, cursor, perm);

    agg_kernel<<<N_NODES, 256, 0, stream>>>(src, etype, perm, row_off,
                                            el, er, ee, feat, a_out, rst);
}

// Round 4
// 457.034 us; speedup vs baseline: 2.1649x; 1.1921x over previous
//
#include <hip/hip_runtime.h>

#define N_NODES 50000
#define E_EDGES 800000
#define IN_DIM 256
#define H_HEADS 4
#define F_OUT 64
#define EF_DIM 64
#define NT_TYPES 8
#define SLOPE 0.2f
#define HF 256  /* H*F */

typedef __attribute__((ext_vector_type(8))) short short8;
typedef __attribute__((ext_vector_type(4))) float f32x4;
typedef unsigned short ushort_t;

// workspace layout (float element offsets)
#define FEATBF_OFF 0          /* N*HF bf16 = 12.8M ushorts = 6.4M floats */
#define EL_OFF   6400000      /* N*H = 200,000 */
#define ER_OFF   6600000
#define EE_OFF   6800000      /* 32, padded to 64 */
#define BT_OFF   6800064      /* 256x256 bf16 = 32768 floats */
#define INT_OFF  6832832
// int offsets within int region
#define DEG_IOFF     0        /* 50,000 */
#define CURSOR_IOFF  50000    /* 50,000 (adjacent: zeroed together) */
#define ROWOFF_IOFF  100000   /* 50,001 -> pad to 50,008 */
#define SSRC_IOFF    150008   /* 800,000 src sorted by dst */
#define SETY_IOFF    950008   /* 800,000 etype sorted by dst */
#define EID_IOFF     1750008  /* 800,000 original edge id */

#define NBLK_GEMM 782         /* ceil(50000/64) */
#define NBLK_HIST 3125        /* 800000/256 exactly */

__device__ __forceinline__ ushort_t f2bf(float f) {
    unsigned u = __float_as_uint(f);
    u += 0x7fffu + ((u >> 16) & 1u);   // round-nearest-even
    return (ushort_t)(u >> 16);
}
__device__ __forceinline__ float bf2f(ushort_t b) {
    return __uint_as_float(((unsigned)b) << 16);
}

// ======================= K1: ee + cast_w + zero(deg,cursor) =======================
// block 0: ee ; blocks 1..256: cast_w (k = b-1) ; blocks 257..647: zero 2*N ints
__global__ __launch_bounds__(256) void k1_prep(
    const float* __restrict__ edge_emb, const float* __restrict__ fc_e_w,
    const float* __restrict__ attn_e, const float* __restrict__ fc_w,
    float* __restrict__ ee, ushort_t* __restrict__ Bt, int* __restrict__ zero_region)
{
    const int b = blockIdx.x;
    if (b == 0) {
        const int c = threadIdx.x;
        const float ae = attn_e[c];
        const int lane = c & 63, h = c >> 6;
        for (int ty = 0; ty < NT_TYPES; ty++) {
            float v = 0.f;
            #pragma unroll 8
            for (int k = 0; k < EF_DIM; k++)
                v = fmaf(edge_emb[ty * EF_DIM + k], fc_e_w[k * (H_HEADS * EF_DIM) + c], v);
            float contrib = v * ae;
            #pragma unroll
            for (int m = 32; m >= 1; m >>= 1) contrib += __shfl_xor(contrib, m);
            if (lane == 0) ee[ty * H_HEADS + h] = contrib;
        }
    } else if (b <= 256) {
        const int k = b - 1, c = threadIdx.x;
        Bt[(size_t)c * 256 + k] = f2bf(fc_w[(size_t)k * 256 + c]);
    } else {
        int idx = (b - 257) * 256 + threadIdx.x;
        if (idx < 2 * N_NODES) zero_region[idx] = 0;
    }
}

// ======================= K2: MFMA GEMM (blocks < NBLK_GEMM) || hist =======================
__device__ __forceinline__ void gemm_body(
    const float* __restrict__ nfeat, const ushort_t* __restrict__ Bt,
    const float* __restrict__ attn_l, const float* __restrict__ attn_r,
    ushort_t* __restrict__ feat, float* __restrict__ el, float* __restrict__ er,
    int blk)
{
    const int w    = threadIdx.x >> 6;   // wave id == head
    const int lane = threadIdx.x & 63;
    const int n16  = lane & 15;
    const int quad = lane >> 4;
    const int row0 = blk * 64;

    f32x4 acc[4][4];
    #pragma unroll
    for (int rt = 0; rt < 4; rt++)
        #pragma unroll
        for (int ct = 0; ct < 4; ct++)
            acc[rt][ct] = (f32x4){0.f, 0.f, 0.f, 0.f};

    for (int kb = 0; kb < IN_DIM; kb += 32) {
        short8 a[4], b[4];
        #pragma unroll
        for (int rt = 0; rt < 4; rt++) {
            int r = row0 + rt * 16 + n16;
            r = r < N_NODES ? r : N_NODES - 1;          // clamp (tail block)
            const float* p = nfeat + (size_t)r * IN_DIM + kb + quad * 8;
            const float4 v0 = *(const float4*)p;
            const float4 v1 = *(const float4*)(p + 4);
            short8 t;
            t[0] = (short)f2bf(v0.x); t[1] = (short)f2bf(v0.y);
            t[2] = (short)f2bf(v0.z); t[3] = (short)f2bf(v0.w);
            t[4] = (short)f2bf(v1.x); t[5] = (short)f2bf(v1.y);
            t[6] = (short)f2bf(v1.z); t[7] = (short)f2bf(v1.w);
            a[rt] = t;
        }
        #pragma unroll
        for (int ct = 0; ct < 4; ct++) {
            const int c = w * 64 + ct * 16 + n16;
            b[ct] = *(const short8*)(Bt + (size_t)c * 256 + kb + quad * 8);
        }
        #pragma unroll
        for (int rt = 0; rt < 4; rt++)
            #pragma unroll
            for (int ct = 0; ct < 4; ct++)
                acc[rt][ct] = __builtin_amdgcn_mfma_f32_16x16x32_bf16(a[rt], b[ct], acc[rt][ct], 0, 0, 0);
    }

    float alv[4], arv[4];
    #pragma unroll
    for (int ct = 0; ct < 4; ct++) {
        alv[ct] = attn_l[w * 64 + ct * 16 + n16];
        arv[ct] = attn_r[w * 64 + ct * 16 + n16];
    }
    #pragma unroll
    for (int rt = 0; rt < 4; rt++) {
        #pragma unroll
        for (int reg = 0; reg < 4; reg++) {
            const int row = row0 + rt * 16 + quad * 4 + reg;
            const bool ok = row < N_NODES;
            float pl = 0.f, pr = 0.f;
            #pragma unroll
            for (int ct = 0; ct < 4; ct++) {
                const float v = acc[rt][ct][reg];
                if (ok) feat[(size_t)row * HF + w * 64 + ct * 16 + n16] = f2bf(v);
                pl = fmaf(v, alv[ct], pl);
                pr = fmaf(v, arv[ct], pr);
            }
            #pragma unroll
            for (int m = 8; m >= 1; m >>= 1) {
                pl += __shfl_xor(pl, m);
                pr += __shfl_xor(pr, m);
            }
            if (n16 == 0 && ok) {
                el[row * H_HEADS + w] = pl;
                er[row * H_HEADS + w] = pr;
            }
        }
    }
}

__global__ __launch_bounds__(256) void k2_gemm_hist(
    const float* __restrict__ nfeat, const ushort_t* __restrict__ Bt,
    const float* __restrict__ attn_l, const float* __restrict__ attn_r,
    ushort_t* __restrict__ feat, float* __restrict__ el, float* __restrict__ er,
    const int* __restrict__ dst, int* __restrict__ deg)
{
    if (blockIdx.x < NBLK_GEMM) {
        gemm_body(nfeat, Bt, attn_l, attn_r, feat, el, er, blockIdx.x);
    } else {
        const int t = (blockIdx.x - NBLK_GEMM) * 256 + threadIdx.x;
        if (t < E_EDGES) atomicAdd(deg + dst[t], 1);
    }
}

// ======================= K3: block-wide scan (1 block, 1024 threads) =======================
#define SCAN_CH 49  /* 1024*49 >= 50000 */
__global__ __launch_bounds__(1024) void scan_kernel(
    const int* __restrict__ deg, int* __restrict__ row_off)
{
    __shared__ int part[1024];
    const int t = threadIdx.x;
    const int start = t * SCAN_CH;
    int s = 0;
    for (int j = 0; j < SCAN_CH; j++) {
        const int g = start + j;
        if (g < N_NODES) s += deg[g];
    }
    part[t] = s;
    __syncthreads();
    int val = s;
    for (int o = 1; o < 1024; o <<= 1) {
        int v = (t >= o) ? part[t - o] : 0;
        __syncthreads();
        val += v;
        part[t] = val;
        __syncthreads();
    }
    int running = val - s;  // exclusive prefix
    for (int j = 0; j < SCAN_CH; j++) {
        const int g = start + j;
        if (g >= N_NODES) break;
        row_off[g] = running;
        running += deg[g];
    }
    if (start <= N_NODES && N_NODES < start + SCAN_CH) row_off[N_NODES] = running;
}

// ======================= K4: scatter -> dst-sorted edge arrays =======================
__global__ __launch_bounds__(256) void scatter_kernel(
    const int* __restrict__ src, const int* __restrict__ dst, const int* __restrict__ etype,
    const int* __restrict__ row_off, int* __restrict__ cursor,
    int* __restrict__ ssrc, int* __restrict__ sety, int* __restrict__ eidA)
{
    const int t = blockIdx.x * 256 + threadIdx.x;
    if (t >= E_EDGES) return;
    const int d = dst[t];
    const int pos = row_off[d] + atomicAdd(cursor + d, 1);
    ssrc[pos] = src[t];
    sety[pos] = etype[t];
    eidA[pos] = t;
}

// ======================= K5: fused softmax + aggregation =======================
__global__ __launch_bounds__(256) void agg_kernel(
    const int* __restrict__ ssrc, const int* __restrict__ sety, const int* __restrict__ eidA,
    const int* __restrict__ row_off,
    const float* __restrict__ el, const float* __restrict__ er,
    const float* __restrict__ ee, const ushort_t* __restrict__ feat,
    float* __restrict__ a_out, float* __restrict__ rst)
{
    const int d = blockIdx.x;
    const int t = threadIdx.x;
    const int h = t >> 6, lane = t & 63;
    const int off = row_off[d];
    const int deg = row_off[d + 1] - off;

    __shared__ int sS[256];
    __shared__ int sE[256];
    __shared__ float sc[4][256];

    if (deg <= 256) {
        if (t < deg) {
            const int s  = ssrc[off + t];
            const int ty = sety[off + t];
            sS[t] = s;
            sE[t] = eidA[off + t];
            const float4 el4 = *(const float4*)(el + s * 4);
            const float4 er4 = *(const float4*)(er + d * 4);
            const float4 ee4 = *(const float4*)(ee + ty * 4);
            float v;
            v = el4.x + er4.x + ee4.x; sc[0][t] = v > 0.f ? v : SLOPE * v;
            v = el4.y + er4.y + ee4.y; sc[1][t] = v > 0.f ? v : SLOPE * v;
            v = el4.z + er4.z + ee4.z; sc[2][t] = v > 0.f ? v : SLOPE * v;
            v = el4.w + er4.w + ee4.w; sc[3][t] = v > 0.f ? v : SLOPE * v;
        }
        __syncthreads();

        float m = -INFINITY;
        for (int i = lane; i < deg; i += 64) m = fmaxf(m, sc[h][i]);
        #pragma unroll
        for (int w = 32; w >= 1; w >>= 1) m = fmaxf(m, __shfl_xor(m, w));

        float s = 0.f;
        for (int i = lane; i < deg; i += 64) s += __expf(sc[h][i] - m);
        #pragma unroll
        for (int w = 32; w >= 1; w >>= 1) s += __shfl_xor(s, w);
        const float inv = 1.f / s;

        // normalize in LDS (component h touched only by wave h: no barrier needed)
        for (int i = lane; i < deg; i += 64) {
            const float a = __expf(sc[h][i] - m) * inv;
            sc[h][i] = a;
            a_out[sE[i] * 4 + h] = a;
        }

        // aggregation: 4 independent gathers in flight
        const ushort_t* fb = feat + h * 64 + lane;
        float acc = 0.f;
        int i = 0;
        for (; i + 4 <= deg; i += 4) {
            const int s0 = sS[i], s1 = sS[i + 1], s2 = sS[i + 2], s3 = sS[i + 3];
            const float a0 = sc[h][i], a1 = sc[h][i + 1], a2 = sc[h][i + 2], a3 = sc[h][i + 3];
            const float v0 = bf2f(fb[(size_t)s0 * HF]);
            const float v1 = bf2f(fb[(size_t)s1 * HF]);
            const float v2 = bf2f(fb[(size_t)s2 * HF]);
            const float v3 = bf2f(fb[(size_t)s3 * HF]);
            acc = fmaf(a0, v0, acc);
            acc = fmaf(a1, v1, acc);
            acc = fmaf(a2, v2, acc);
            acc = fmaf(a3, v3, acc);
        }
        for (; i < deg; i++)
            acc = fmaf(sc[h][i], bf2f(fb[(size_t)sS[i] * HF]), acc);
        rst[(size_t)d * HF + h * 64 + lane] = acc;
    } else {
        // fallback for deg > 256 (not expected with this graph; correctness insurance)
        const float erh = er[d * 4 + h];
        float m = -INFINITY;
        for (int i = lane; i < deg; i += 64) {
            float v = el[ssrc[off + i] * 4 + h] + erh + ee[sety[off + i] * 4 + h];
            v = v > 0.f ? v : SLOPE * v;
            m = fmaxf(m, v);
        }
        #pragma unroll
        for (int w = 32; w >= 1; w >>= 1) m = fmaxf(m, __shfl_xor(m, w));
        float s = 0.f;
        for (int i = lane; i < deg; i += 64) {
            float v = el[ssrc[off + i] * 4 + h] + erh + ee[sety[off + i] * 4 + h];
            v = v > 0.f ? v : SLOPE * v;
            s += __expf(v - m);
        }
        #pragma unroll
        for (int w = 32; w >= 1; w >>= 1) s += __shfl_xor(s, w);
        const float inv = 1.f / s;
        float acc = 0.f;
        for (int i = 0; i < deg; i++) {
            const int sn = ssrc[off + i];
            float v = el[sn * 4 + h] + erh + ee[sety[off + i] * 4 + h];
            v = v > 0.f ? v : SLOPE * v;
            const float a = __expf(v - m) * inv;
            if (lane == 0) a_out[eidA[off + i] * 4 + h] = a;
            acc = fmaf(a, bf2f(feat[(size_t)sn * HF + h * 64 + lane]), acc);
        }
        rst[(size_t)d * HF + h * 64 + lane] = acc;
    }
}

extern "C" void kernel_launch(void* const* d_in, const int* in_sizes, int n_in,
                              void* d_out, int out_size, void* d_ws, size_t ws_size,
                              hipStream_t stream) {
    const float* nfeat    = (const float*)d_in[0];
    const float* fc_w     = (const float*)d_in[1];
    const float* fc_e_w   = (const float*)d_in[2];
    const float* attn_l   = (const float*)d_in[3];
    const float* attn_r   = (const float*)d_in[4];
    const float* attn_e   = (const float*)d_in[5];
    const float* edge_emb = (const float*)d_in[6];
    const int*   src      = (const int*)d_in[7];
    const int*   dst      = (const int*)d_in[8];
    const int*   etype    = (const int*)d_in[9];

    float* ws = (float*)d_ws;
    ushort_t* feat = (ushort_t*)(ws + FEATBF_OFF);
    float* el   = ws + EL_OFF;
    float* er   = ws + ER_OFF;
    float* ee   = ws + EE_OFF;
    ushort_t* Bt = (ushort_t*)(ws + BT_OFF);
    int*   ip      = (int*)(ws + INT_OFF);
    int*   deg     = ip + DEG_IOFF;
    int*   cursor  = ip + CURSOR_IOFF;
    int*   row_off = ip + ROWOFF_IOFF;
    int*   ssrc    = ip + SSRC_IOFF;
    int*   sety    = ip + SETY_IOFF;
    int*   eidA    = ip + EID_IOFF;

    float* rst   = (float*)d_out;                              // [N,H,F]
    float* a_out = (float*)d_out + (size_t)N_NODES * HF;       // [E,H]

    // K1: ee (1 blk) + cast_w (256 blks) + zero deg/cursor (391 blks)
    k1_prep<<<257 + 391, 256, 0, stream>>>(edge_emb, fc_e_w, attn_e, fc_w, ee, Bt, deg);
    // K2: gemm (782 blks) || hist (3125 blks)
    k2_gemm_hist<<<NBLK_GEMM + NBLK_HIST, 256, 0, stream>>>(
        nfeat, Bt, attn_l, attn_r, feat, el, er, dst, deg);
    // K3: scan
    scan_kernel<<<1, 1024, 0, stream>>>(deg, row_off);
    // K4: scatter into dst-sorted arrays
    scatter_kernel<<<NBLK_HIST, 256, 0, stream>>>(src, dst, etype, row_off, cursor,
                                                  ssrc, sety, eidA);
    // K5: fused softmax + aggregation
    agg_kernel<<<N_NODES, 256, 0, stream>>>(ssrc, sety, eidA, row_off,
                                            el, er, ee, feat, a_out, rst);
}